// Round 4
// baseline (282.162 us; speedup 1.0000x reference)
//
#include <hip/hip_runtime.h>

#define N_BITS    64
#define N_GROUPS  8
#define PDIM      8
#define MAX_TABLE 32768
#define BATCH     524288

// Native clang vector types — required by __builtin_nontemporal_load/store
// (HIP_vector_type structs are rejected by the builtin).
typedef int   vi4 __attribute__((ext_vector_type(4)));
typedef float vf4 __attribute__((ext_vector_type(4)));

// ---------------------------------------------------------------------------
// Pass 1: transpose group_tables (8, 8, 32768) -> tt (8, 32768, 8) so the 8
// p-values for one addr are contiguous (32 B, 32 B-aligned => single 64 B line).
// Side benefit: warms per-XCD L2 with the table right before the mapper pass.
// ---------------------------------------------------------------------------
__global__ __launch_bounds__(256) void transpose_tables(
    const float* __restrict__ gt,   // (8, 8, 32768)
    float*       __restrict__ tt)   // (8, 32768, 8)
{
    const int i  = blockIdx.x * blockDim.x + threadIdx.x;   // 0 .. 524287
    const int a4 = i & (MAX_TABLE / 4 - 1);                 // addr/4 within row
    const int gp = i >> 13;                                 // 0..63
    const int p  = gp & 7;
    const int g  = gp >> 3;

    const vf4 v = reinterpret_cast<const vf4*>(gt)[i];      // coalesced
    const int a = a4 * 4;
    float* base = tt + (size_t)g * MAX_TABLE * PDIM + p;
    base[(size_t)(a + 0) * PDIM] = v.x;
    base[(size_t)(a + 1) * PDIM] = v.y;
    base[(size_t)(a + 2) * PDIM] = v.z;
    base[(size_t)(a + 3) * PDIM] = v.w;
}

// ---------------------------------------------------------------------------
// Pass 2: one thread per (batch element, group); 8 consecutive lanes = element.
// Streaming traffic (bits in, out) is non-temporal to keep L2 for the table.
// ---------------------------------------------------------------------------
__global__ __launch_bounds__(256) void comp_mapper_kernel(
    const int*   __restrict__ bits,   // (BATCH, 64) 0/1 int32
    const float* __restrict__ tab,    // (8, 32768, 8) transposed
    const int*   __restrict__ ct,     // (7, 256) 0/1 int32
    float*       __restrict__ out)    // (BATCH, 64) fp32
{
    const int tid = blockIdx.x * blockDim.x + threadIdx.x;   // 0 .. BATCH*8-1
    const int g   = tid & 7;

    // load this group's 8 bits (32 contiguous bytes per thread), nt: streaming
    const vi4* bp = reinterpret_cast<const vi4*>(bits) + (size_t)tid * 2;
    vi4 x = __builtin_nontemporal_load(bp);
    vi4 y = __builtin_nontemporal_load(bp + 1);

    // gaddr: bit j (j=0 first) has weight 2^(7-j)
    int gaddr = (x.x << 7) | (x.y << 6) | (x.z << 5) | (x.w << 4)
              | (y.x << 3) | (y.y << 2) | (y.z << 1) |  y.w;

    // per-group carry (groups 0..6 only)
    int carry = 0;
    if (g < 7) carry = ct[g * 256 + gaddr];

    // exchange carries across the element's 8 lanes via ballot
    unsigned long long m = __ballot(carry);
    const int lane = threadIdx.x & 63;
    const int base = lane & ~7;                       // element's lane-0
    unsigned f = (unsigned)((m >> base) & 0xFFull);   // bit j = carry of group j
    // v = sum_{j<g} c_j * 2^(g-1-j)  ==  brev8(f) >> (8-g)   (g=0 -> 0)
    unsigned v = (__brev(f) >> 24) >> (8 - g);

    const int addr = (gaddr << g) | (int)v;           // < 2^(8+g) <= 32768

    // 32 contiguous, 32B-aligned bytes: exactly one 64B line per thread (cached)
    const vf4* t = reinterpret_cast<const vf4*>(
        tab + ((size_t)g * MAX_TABLE + addr) * PDIM);
    vf4 o0 = t[0];
    vf4 o1 = t[1];

    // coalesced store: 32 contiguous bytes per thread, nt: streaming
    vf4* op = reinterpret_cast<vf4*>(out) + (size_t)tid * 2;
    __builtin_nontemporal_store(o0, op);
    __builtin_nontemporal_store(o1, op + 1);
}

extern "C" void kernel_launch(void* const* d_in, const int* in_sizes, int n_in,
                              void* d_out, int out_size, void* d_ws, size_t ws_size,
                              hipStream_t stream) {
    const int*   bits = (const int*)  d_in[0];
    const float* gt   = (const float*)d_in[1];
    const int*   ct   = (const int*)  d_in[2];
    float*       out  = (float*)      d_out;

    const int total_threads = BATCH * N_GROUPS;       // 4,194,304
    const int block = 256;
    const int grid  = total_threads / block;          // 16384

    float* tt = (float*)d_ws;                         // 8 MiB, ws guaranteed
    const int t_threads = N_GROUPS * PDIM * MAX_TABLE / 4;   // 524288
    transpose_tables<<<t_threads / block, block, 0, stream>>>(gt, tt);
    comp_mapper_kernel<<<grid, block, 0, stream>>>(bits, tt, ct, out);
}

// Round 5
// 266.409 us; speedup vs baseline: 1.0591x; 1.0591x over previous
//
#include <hip/hip_runtime.h>

#define N_BITS    64
#define N_GROUPS  8
#define PDIM      8
#define MAX_TABLE 32768
#define BATCH     524288
#define HALF      (BATCH / 2)

// Native clang vector types — required by __builtin_nontemporal_load/store.
typedef int   vi4 __attribute__((ext_vector_type(4)));
typedef float vf4 __attribute__((ext_vector_type(4)));

// ---------------------------------------------------------------------------
// Pass 1: transpose + COMPACT group_tables (8, 8, 32768) -> tt.
// Group g only ever uses addr < 2^(8+g), so pack row g at entry offset
// 256*(2^g - 1): total live table = 65280 entries * 32 B = 2.04 MiB, which is
// L2-resident on every XCD (4 MiB/XCD). Entry = 8 contiguous p-values (32 B).
// ---------------------------------------------------------------------------
__global__ __launch_bounds__(256) void transpose_tables(
    const float* __restrict__ gt,   // (8, 8, 32768)
    float*       __restrict__ tt)   // compact (65280, 8)
{
    const int i  = blockIdx.x * blockDim.x + threadIdx.x;   // 0 .. 524287
    const int a4 = i & (MAX_TABLE / 4 - 1);                 // addr/4 within row
    const int gp = i >> 13;                                 // 0..63
    const int p  = gp & 7;
    const int g  = gp >> 3;
    const int a  = a4 * 4;
    if (a >= (256 << g)) return;                            // beyond live prefix

    const vf4 v = reinterpret_cast<const vf4*>(gt)[i];      // coalesced
    const int ro = 256 * ((1 << g) - 1);                    // compact row offset
    float* base = tt + (size_t)(ro + a) * PDIM + p;
    base[0 * PDIM] = v.x;
    base[1 * PDIM] = v.y;
    base[2 * PDIM] = v.z;
    base[3 * PDIM] = v.w;
}

// ---------------------------------------------------------------------------
// Pass 2: one thread per (element, group, half-of-8), two elements per thread
// (e and e+HALF) for ILP. tid = e*16 + g*2 + h, so the output float4 index for
// element A is exactly tid -> every store instruction covers contiguous full
// 64 B lines (nt write-through with no partial-line overhead).
// Carries: 16 consecutive lanes = one element; ballot bits 2g,2g+1 both hold
// carry_g (twins agree); even-bit Morton compress recovers the 8-bit field.
// ---------------------------------------------------------------------------
__global__ __launch_bounds__(256) void comp_mapper_kernel(
    const int*   __restrict__ bits,   // (BATCH, 64) 0/1 int32
    const float* __restrict__ tab,    // compact transposed table
    const int*   __restrict__ ct,     // (7, 256) 0/1 int32
    float*       __restrict__ out)    // (BATCH, 64) fp32
{
    const int tid  = blockIdx.x * blockDim.x + threadIdx.x; // 0 .. BATCH*8-1
    const int h    = tid & 1;
    const int g    = (tid >> 1) & 7;
    const int lane = threadIdx.x & 63;

    // bits for (element, group): vi4 index e*16 + g*2 (twins load same 32 B)
    const size_t biA = (size_t)(tid >> 4) * 16 + (size_t)g * 2;
    const vi4* bpA = reinterpret_cast<const vi4*>(bits) + biA;
    const vi4* bpB = bpA + (size_t)HALF * 16;
    vi4 xa = __builtin_nontemporal_load(bpA);
    vi4 ya = __builtin_nontemporal_load(bpA + 1);
    vi4 xb = __builtin_nontemporal_load(bpB);
    vi4 yb = __builtin_nontemporal_load(bpB + 1);

    // gaddr: bit j (j=0 first) has weight 2^(7-j)
    int ga = (xa.x << 7) | (xa.y << 6) | (xa.z << 5) | (xa.w << 4)
           | (ya.x << 3) | (ya.y << 2) | (ya.z << 1) |  ya.w;
    int gb = (xb.x << 7) | (xb.y << 6) | (xb.z << 5) | (xb.w << 4)
           | (yb.x << 3) | (yb.y << 2) | (yb.z << 1) |  yb.w;

    // per-group carry (groups 0..6 only); ct is 7 KiB -> L1-resident
    int cA = 0, cB = 0;
    if (g < 7) {
        cA = ct[g * 256 + ga];
        cB = ct[g * 256 + gb];
    }

    // 16-lane carry exchange
    unsigned long long mA = __ballot(cA);
    unsigned long long mB = __ballot(cB);
    const int base = lane & ~15;
    unsigned fA = (unsigned)((mA >> base) & 0xFFFFull);  // bits 2j,2j+1 = c_j
    unsigned fB = (unsigned)((mB >> base) & 0xFFFFull);

    // even-bit compress: c_j moves from bit 2j to bit j
    unsigned eA = fA & 0x5555u;
    eA = (eA | (eA >> 1)) & 0x3333u;
    eA = (eA | (eA >> 2)) & 0x0F0Fu;
    eA = (eA | (eA >> 4)) & 0x00FFu;
    unsigned eB = fB & 0x5555u;
    eB = (eB | (eB >> 1)) & 0x3333u;
    eB = (eB | (eB >> 2)) & 0x0F0Fu;
    eB = (eB | (eB >> 4)) & 0x00FFu;

    // v = sum_{j<g} c_j * 2^(g-1-j) = brev8(field) >> (8-g)   (g=0 -> 0)
    unsigned vA = (__brev(eA) >> 24) >> (8 - g);
    unsigned vB = (__brev(eB) >> 24) >> (8 - g);

    const int addrA = (ga << g) | (int)vA;
    const int addrB = (gb << g) | (int)vB;

    // gathers: one 16 B load each from the 2 MiB L2-resident compact table
    const int ro = 256 * ((1 << g) - 1);
    const vf4* tt4 = reinterpret_cast<const vf4*>(tab);
    vf4 oA = tt4[(size_t)(ro + addrA) * 2 + h];
    vf4 oB = tt4[(size_t)(ro + addrB) * 2 + h];

    // stores: float4 index A = tid exactly -> contiguous full lines, nt
    vf4* op = reinterpret_cast<vf4*>(out);
    __builtin_nontemporal_store(oA, op + tid);
    __builtin_nontemporal_store(oB, op + tid + (size_t)HALF * 16);
}

extern "C" void kernel_launch(void* const* d_in, const int* in_sizes, int n_in,
                              void* d_out, int out_size, void* d_ws, size_t ws_size,
                              hipStream_t stream) {
    const int*   bits = (const int*)  d_in[0];
    const float* gt   = (const float*)d_in[1];
    const int*   ct   = (const int*)  d_in[2];
    float*       out  = (float*)      d_out;

    const int block = 256;

    float* tt = (float*)d_ws;                                // 2.04 MiB used
    const int t_threads = N_GROUPS * PDIM * MAX_TABLE / 4;   // 524288
    transpose_tables<<<t_threads / block, block, 0, stream>>>(gt, tt);

    const int total_threads = BATCH * N_GROUPS;              // 4,194,304
    comp_mapper_kernel<<<total_threads / block, block, 0, stream>>>(bits, tt, ct, out);
}

// Round 6
// 259.234 us; speedup vs baseline: 1.0884x; 1.0277x over previous
//
#include <hip/hip_runtime.h>

#define N_GROUPS  8
#define PDIM      8
#define MAX_TABLE 32768
#define BATCH     524288
#define QUART     (BATCH / 4)

// Native clang vector types — required by __builtin_nontemporal_load/store.
typedef int   vi4 __attribute__((ext_vector_type(4)));
typedef float vf4 __attribute__((ext_vector_type(4)));

#define TT_FLOATS (65280 * 8)   // compact table: 522240 floats = 2.04 MiB

// ---------------------------------------------------------------------------
// Pass 1: (a) transpose + compact group_tables (8,8,32768) -> tt (65280,8):
// group g only uses addr < 2^(8+g); row g starts at entry 256*(2^g - 1).
// (b) block 0 additionally bit-packs carry_tables (7,256) int32 0/1 into
// 28 uint64s (224 B) so the mapper's carry lookup is a 4-line L1-resident
// table instead of ~30 scattered line-requests per wave.
// ---------------------------------------------------------------------------
__global__ __launch_bounds__(256) void transpose_tables(
    const float* __restrict__ gt,   // (8, 8, 32768)
    const int*   __restrict__ ct,   // (7, 256) 0/1 int32
    float*       __restrict__ tt,   // compact (65280, 8)
    unsigned long long* __restrict__ ctpack)  // 28 x u64
{
    if (blockIdx.x == 0 && threadIdx.x < 28) {
        const int g = threadIdx.x >> 2, w = threadIdx.x & 3;
        const int* src = ct + g * 256 + w * 64;
        unsigned long long m = 0;
        #pragma unroll 8
        for (int b = 0; b < 64; ++b)
            m |= (unsigned long long)(src[b] & 1) << b;
        ctpack[threadIdx.x] = m;
    }

    const int i  = blockIdx.x * blockDim.x + threadIdx.x;   // 0 .. 524287
    const int a4 = i & (MAX_TABLE / 4 - 1);
    const int gp = i >> 13;
    const int p  = gp & 7;
    const int g  = gp >> 3;
    const int a  = a4 * 4;
    if (a >= (256 << g)) return;                            // beyond live prefix

    const vf4 v = reinterpret_cast<const vf4*>(gt)[i];      // coalesced
    const int ro = 256 * ((1 << g) - 1);                    // compact row offset
    float* base = tt + (size_t)(ro + a) * PDIM + p;
    base[0 * PDIM] = v.x;
    base[1 * PDIM] = v.y;
    base[2 * PDIM] = v.z;
    base[3 * PDIM] = v.w;
}

// ---------------------------------------------------------------------------
// Pass 2: one thread per (element, group, half), FOUR elements per thread
// (eq + k*QUART, k=0..3) for ILP. tid = eq*16 + g*2 + h, so element k's
// output float4 index is tid + k*QUART*16 -> every store instruction covers
// contiguous full 64 B lines (nt write-through, no partial-line overhead).
// Carry exchange: 16 consecutive lanes = one element; ballot bits 2j,2j+1
// both hold carry_j; even-bit compress recovers the 8-bit field.
// ---------------------------------------------------------------------------
__global__ __launch_bounds__(256) void comp_mapper_kernel(
    const int*   __restrict__ bits,   // (BATCH, 64) 0/1 int32
    const float* __restrict__ tab,    // compact transposed table (L2-resident)
    const unsigned long long* __restrict__ ctpack,  // 28 x u64 (L1-resident)
    float*       __restrict__ out)    // (BATCH, 64) fp32
{
    const int tid  = blockIdx.x * blockDim.x + threadIdx.x; // 0 .. QUART*16-1
    const int h    = tid & 1;
    const int g    = (tid >> 1) & 7;
    const int lane = threadIdx.x & 63;
    const int base = lane & ~15;
    const size_t bi0 = (size_t)(tid >> 4) * 16 + (size_t)g * 2;
    const int ro = 256 * ((1 << g) - 1);

    int addrv[4];

    #pragma unroll
    for (int k = 0; k < 4; ++k) {
        const vi4* bp = reinterpret_cast<const vi4*>(bits)
                      + bi0 + (size_t)k * QUART * 16;
        vi4 x = __builtin_nontemporal_load(bp);
        vi4 y = __builtin_nontemporal_load(bp + 1);

        // gaddr: bit j (j=0 first) has weight 2^(7-j)
        int ga = (x.x << 7) | (x.y << 6) | (x.z << 5) | (x.w << 4)
               | (y.x << 3) | (y.y << 2) | (y.z << 1) |  y.w;

        // carry from bit-packed table (groups 0..6; g==7 contributes 0)
        int c = 0;
        if (g < 7) c = (int)((ctpack[g * 4 + (ga >> 6)] >> (ga & 63)) & 1ull);

        unsigned long long m = __ballot(c);
        unsigned f = (unsigned)((m >> base) & 0xFFFFull);  // bits 2j,2j+1 = c_j
        unsigned e = f & 0x5555u;                          // even-bit compress
        e = (e | (e >> 1)) & 0x3333u;
        e = (e | (e >> 2)) & 0x0F0Fu;
        e = (e | (e >> 4)) & 0x00FFu;
        // v = sum_{j<g} c_j * 2^(g-1-j) = brev8(field) >> (8-g)   (g=0 -> 0)
        unsigned v = (__brev(e) >> 24) >> (8 - g);

        addrv[k] = (ga << g) | (int)v;
    }

    const vf4* tt4 = reinterpret_cast<const vf4*>(tab);
    vf4* op = reinterpret_cast<vf4*>(out);
    #pragma unroll
    for (int k = 0; k < 4; ++k) {
        // one 16 B load from the 2 MiB compact table (twins share the line)
        vf4 o = tt4[(size_t)(ro + addrv[k]) * 2 + h];
        __builtin_nontemporal_store(o, op + tid + (size_t)k * QUART * 16);
    }
}

extern "C" void kernel_launch(void* const* d_in, const int* in_sizes, int n_in,
                              void* d_out, int out_size, void* d_ws, size_t ws_size,
                              hipStream_t stream) {
    const int*   bits = (const int*)  d_in[0];
    const float* gt   = (const float*)d_in[1];
    const int*   ct   = (const int*)  d_in[2];
    float*       out  = (float*)      d_out;

    const int block = 256;

    float* tt = (float*)d_ws;
    unsigned long long* ctpack =
        (unsigned long long*)((char*)d_ws + (size_t)TT_FLOATS * sizeof(float));

    const int t_threads = N_GROUPS * PDIM * MAX_TABLE / 4;   // 524288
    transpose_tables<<<t_threads / block, block, 0, stream>>>(gt, ct, tt, ctpack);

    const int m_threads = QUART * 16;                        // 2,097,152
    comp_mapper_kernel<<<m_threads / block, block, 0, stream>>>(bits, tt, ctpack, out);
}